// Round 16
// baseline (430.139 us; speedup 1.0000x reference)
//
#include <hip/hip_runtime.h>
#include <hip/hip_bf16.h>

#define NN 6000
#define NPAD 6016      // 94*64
#define DF 512
#define HID 256
#define NH 8
#define NC 32
#define FTOT 2048
#define MSTR 96        // u64 words per mask row
#define NJB (NPAD / 64)
#define NJT (NPAD / 32)
#define L2E 1.4426950408889634f

using short8 = __attribute__((ext_vector_type(8))) short;
using f32x16 = __attribute__((ext_vector_type(16))) float;
using f32x4  = __attribute__((ext_vector_type(4))) float;

__device__ __forceinline__ unsigned short f2bf(float f) {
    unsigned int u = __float_as_uint(f);
    return (unsigned short)((u + 0x7fffu + ((u >> 16) & 1u)) >> 16);
}
__device__ __forceinline__ float bf2f(unsigned short s) {
    return __uint_as_float(((unsigned int)s) << 16);
}
// async global->LDS, 16B per lane
__device__ __forceinline__ void gl16(const void* g, void* l) {
    __builtin_amdgcn_global_load_lds(
        (const __attribute__((address_space(1))) unsigned int*)g,
        (__attribute__((address_space(3))) unsigned int*)l, 16, 0, 0);
}

// ---------------- prep kernels (verified r3/r4) ----------------

__global__ void pack_bits(const int* __restrict__ adj, unsigned char* __restrict__ maskb) {
    int row = blockIdx.y;
    int b = blockIdx.x * 256 + threadIdx.x;     // byte index 0..767
    if (b >= 768) return;
    int j0 = b * 8;
    unsigned int v = 0;
    if (j0 + 7 < NN) {
        const int4* p = (const int4*)(adj + (size_t)row * NN + j0);
        int4 a = p[0], c = p[1];
        v = (unsigned)((a.x>0) | ((a.y>0)<<1) | ((a.z>0)<<2) | ((a.w>0)<<3)
          | ((c.x>0)<<4) | ((c.y>0)<<5) | ((c.z>0)<<6) | ((c.w>0)<<7));
    }
    maskb[(size_t)row * 768 + b] = (unsigned char)v;
}

__global__ void cast_x4(const float* __restrict__ x, unsigned short* __restrict__ xb, int n4) {
    int i = blockIdx.x * 256 + threadIdx.x;
    if (i >= n4) return;
    float4 v = ((const float4*)x)[i];
    unsigned long long pk = (unsigned long long)f2bf(v.x)
        | ((unsigned long long)f2bf(v.y) << 16)
        | ((unsigned long long)f2bf(v.z) << 32)
        | ((unsigned long long)f2bf(v.w) << 48);
    ((unsigned long long*)xb)[i] = pk;
}

__global__ void wt_pack(const float* __restrict__ W0, unsigned short* __restrict__ Wt) {
    int fp = blockIdx.x;                 // h*256+f
    int h = fp >> 8, f = fp & 255;
    for (int k = threadIdx.x; k < DF; k += 256)
        Wt[(size_t)fp * DF + k] = f2bf(W0[(((size_t)h * DF + k) << 8) | f]);
}

__global__ void wct_pack(const float* __restrict__ Wc, unsigned short* __restrict__ Wct) {
    int c = blockIdx.x;
    for (int k = threadIdx.x; k < FTOT; k += 256)
        Wct[(size_t)c * FTOT + k] = f2bf(Wc[(size_t)k * NC + c]);
}

// ---------------- GEMM1 (verified r3): Ht[f][i] = sum_k X[i][k] W[k][f] ----------------
__global__ __launch_bounds__(256, 2) void gemm_h(const unsigned short* __restrict__ A,
                                                 const unsigned short* __restrict__ B,
                                                 unsigned short* __restrict__ Ht) {
    __shared__ __align__(16) unsigned short As[128 * 64];
    __shared__ __align__(16) unsigned short Bs[128 * 64];
    const int w = threadIdx.x >> 6, l = threadIdx.x & 63;
    const int lrow = l & 31, kh = l >> 5;
    const int wm = w >> 1, wn = w & 1;
    const int mbase = blockIdx.x * 128, nbase = blockIdx.y * 128;
    const int srcc = (l & 7) ^ (l >> 3);
    f32x16 acc[2][2];
#pragma unroll
    for (int i = 0; i < 2; ++i)
#pragma unroll
        for (int j = 0; j < 2; ++j) acc[i][j] = (f32x16)0.0f;

#pragma unroll 1
    for (int kb = 0; kb < DF / 64; ++kb) {
        __syncthreads();
#pragma unroll
        for (int q = 0; q < 4; ++q) {
            int c = q * 4 + w;
            int r = c * 8 + (l >> 3);
            int arow = mbase + r; if (arow > NN - 1) arow = NN - 1;
            gl16(A + (size_t)arow * DF + kb * 64 + srcc * 8, (char*)As + c * 1024);
            gl16(B + (size_t)(nbase + r) * DF + kb * 64 + srcc * 8, (char*)Bs + c * 1024);
        }
        __syncthreads();
#pragma unroll
        for (int kk = 0; kk < 4; ++kk) {
            short8 av[2], bv[2];
#pragma unroll
            for (int mt = 0; mt < 2; ++mt) {
                int r = wm * 64 + mt * 32 + lrow;
                av[mt] = *(const short8*)((const char*)As + r * 128 + ((((kk << 1) | kh) ^ (r & 7)) << 4));
            }
#pragma unroll
            for (int ft = 0; ft < 2; ++ft) {
                int r = wn * 64 + ft * 32 + lrow;
                bv[ft] = *(const short8*)((const char*)Bs + r * 128 + ((((kk << 1) | kh) ^ (r & 7)) << 4));
            }
#pragma unroll
            for (int mt = 0; mt < 2; ++mt)
#pragma unroll
                for (int ft = 0; ft < 2; ++ft)
                    acc[mt][ft] = __builtin_amdgcn_mfma_f32_32x32x16_bf16(av[mt], bv[ft], acc[mt][ft], 0, 0, 0);
        }
    }
#pragma unroll
    for (int mt = 0; mt < 2; ++mt)
#pragma unroll
        for (int ft = 0; ft < 2; ++ft) {
            size_t n = nbase + wn * 64 + ft * 32 + lrow;
#pragma unroll
            for (int g = 0; g < 4; ++g) {
                int m0 = mbase + wm * 64 + mt * 32 + (g << 3) + (kh << 2);
                unsigned long long pk =
                    (unsigned long long)f2bf(acc[mt][ft][g * 4 + 0]) |
                    ((unsigned long long)f2bf(acc[mt][ft][g * 4 + 1]) << 16) |
                    ((unsigned long long)f2bf(acc[mt][ft][g * 4 + 2]) << 32) |
                    ((unsigned long long)f2bf(acc[mt][ft][g * 4 + 3]) << 48);
                *(unsigned long long*)(Ht + n * NPAD + m0) = pk;
            }
        }
}

// ---------------- f1/f2, pre-scaled by log2e (verified r6) ----------------
__global__ void f12_kern(const unsigned short* __restrict__ Ht, const float* __restrict__ a1,
                         const float* __restrict__ a2, float* __restrict__ f1, float* __restrict__ f2,
                         int fdim) {
    int h = blockIdx.y;
    int i = blockIdx.x * 256 + threadIdx.x;
    if (i >= NPAD) return;
    float s1 = 0.f, s2 = 0.f;
    const unsigned short* base = Ht + (size_t)h * fdim * NPAD + i;
    for (int f = 0; f < fdim; ++f) {
        float v = bf2f(base[(size_t)f * NPAD]);
        s1 = fmaf(v, a1[h * fdim + f], s1);
        s2 = fmaf(v, a2[h * fdim + f], s2);
    }
    f1[(size_t)h * NPAD + i] = s1 * L2E;
    f2[(size_t)h * NPAD + i] = s2 * L2E;
}

// per-head global max -> RA/RB + E2F/E2Fb (verified r14)
__global__ void rarb_kern(const float* __restrict__ f1all, const float* __restrict__ f2all,
                          float* __restrict__ RA, float* __restrict__ RB,
                          float* __restrict__ E2F, float* __restrict__ E2Fb) {
    int h = blockIdx.x;
    __shared__ float red[8];
    const float* f2h = f2all + (size_t)h * NPAD;
    float m = -3.0e38f;
    for (int i = threadIdx.x; i < NN; i += 256) m = fmaxf(m, f2h[i]);
    for (int off = 32; off; off >>= 1) m = fmaxf(m, __shfl_xor(m, off));
    if ((threadIdx.x & 63) == 0) red[threadIdx.x >> 6] = m;
    __syncthreads();
    if (threadIdx.x == 0)
        red[4] = fmaxf(fmaxf(red[0], red[1]), fmaxf(red[2], red[3]));
    __syncthreads();
    float Mh = red[4];
    for (int i = threadIdx.x; i < NPAD; i += 256) {
        float F1 = (i < NN) ? f1all[(size_t)h * NPAD + i] : 0.f;
        float t2 = F1 + Mh;
        float Mi = fmaxf(t2, 0.2f * t2);
        RA[(size_t)h * NPAD + i] = F1 - Mi;
        RB[(size_t)h * NPAD + i] = 0.2f * F1 - Mi;
        float v2 = f2h[i];
        E2F[(size_t)h * NPAD + i] = exp2f(v2);
        E2Fb[(size_t)h * NPAD + i] = exp2f(0.2f * v2);
    }
}

// ---------------- main attention v11: r15 + conflict-free slot involution ----------------
// grid 752: h = bid&7 (head->XCD pin), rowblk = bid>>3 (64 rows, 4 waves x 16).
// Tile [256 f][32 j] = 16 KB, triple-buffered (48 KB). r8-verified loop.
// Swizzle v2 (rule #21 both-sides): stored slot t of row r holds logical seg t^((r>>1)&3).
//   store: segsrc = (l&3) ^ ((l>>3)&3)   (row-in-chunk = l>>2)
//   read:  slot   = s ^ ((fl>>1)&3)
// Bank base = (fl&1)*16 + slot*4 -> 16 lanes cover all 8 (half,slot) pairs twice = 2-way (free).
__global__ __launch_bounds__(256, 3) void attn_main(
    const unsigned short* __restrict__ Ht,
    const unsigned long long* __restrict__ mask,
    const float* __restrict__ RA, const float* __restrict__ RB,
    const float* __restrict__ E2F, const float* __restrict__ E2Fb,
    unsigned short* __restrict__ x2)
{
    __shared__ __align__(16) unsigned short htile[3 * 256 * 32];   // 48 KB: 3 x [256 f][32 j]
    const int bid = blockIdx.x;
    const int h = bid & 7;
    const int rowbase = (bid >> 3) * 64;
    const int w = threadIdx.x >> 6, l = threadIdx.x & 63;
    const int la = l & 15;            // A row within wave's 16-row group
    const int s  = l >> 4;            // k-group (8 j's)
    const int rowA = rowbase + w * 16 + la;
    const int rowAc = (rowA < NN) ? rowA : NN - 1;
    const unsigned short* Hh = Ht + (size_t)h * HID * NPAD;
    const float* E2Fh = E2F + (size_t)h * NPAD;
    const float* E2Fbh = E2Fb + (size_t)h * NPAD;
    const float era = exp2f(RA[(size_t)h * NPAD + rowAc]);
    const float erb = exp2f(RB[(size_t)h * NPAD + rowAc]);
    const short8 ones = { (short)0x3F80, (short)0x3F80, (short)0x3F80, (short)0x3F80,
                          (short)0x3F80, (short)0x3F80, (short)0x3F80, (short)0x3F80 };
    f32x4 acc16[16];
    f32x4 asum4 = (f32x4)0.0f;
#pragma unroll
    for (int i = 0; i < 16; ++i) acc16[i] = (f32x4)0.0f;

    // staging: chunk c (0..15) = rows c*16..c*16+15; lane l -> row c*16+(l>>2), stored slot l&3.
    const int segsrc = (l & 3) ^ ((l >> 3) & 3);
    auto STAGE = [&](int buf, int jt) {
#pragma unroll
        for (int q = 0; q < 4; ++q) {
            int c = q * 4 + w;                       // chunk 0..15
            int f = c * 16 + (l >> 2);               // feature row 0..255
            gl16(Hh + (size_t)f * NPAD + jt * 32 + segsrc * 8,
                 (char*)htile + buf * 16384 + c * 1024);
        }
    };

    STAGE(0, 0);
#pragma unroll 1
    for (int jt = 0; jt < NJT; ++jt) {
        if (jt + 1 < NJT) STAGE((jt + 1) % 3, jt + 1);     // depth-1 prefetch (4 gl16, static)
        asm volatile("s_waitcnt vmcnt(4)" ::: "memory");   // own S(jt) retired; prefetch in flight
        __builtin_amdgcn_sched_barrier(0);
        __builtin_amdgcn_s_barrier();                      // publish tile jt (non-draining)
        __builtin_amdgcn_sched_barrier(0);
        const char* tb = (const char*)htile + (jt % 3) * 16384;
        unsigned int mwrd = ((const unsigned int*)mask)[(size_t)rowAc * 192 + jt];
        unsigned int mbyte = (mwrd >> (s * 8)) & 0xffu;
        int j0 = jt * 32 + s * 8;
        f32x4 ea0 = *(const f32x4*)(E2Fh + j0);
        f32x4 ea1 = *(const f32x4*)(E2Fh + j0 + 4);
        f32x4 eb0 = *(const f32x4*)(E2Fbh + j0);
        f32x4 eb1 = *(const f32x4*)(E2Fbh + j0 + 4);
        float p[8];
#pragma unroll
        for (int e = 0; e < 8; ++e) {
            float fe = (e < 4) ? ea0[e & 3] : ea1[e & 3];
            float fb = (e < 4) ? eb0[e & 3] : eb1[e & 3];
            float pe = fmaxf(era * fe, erb * fb);          // == exp2(max(ra+f, rb+0.2f))
            p[e] = (mbyte & (1u << e)) ? pe : 0.f;
        }
        union { unsigned int u[4]; short8 s8; } cv;
#pragma unroll
        for (int q = 0; q < 4; ++q)
            cv.u[q] = __builtin_amdgcn_perm(__float_as_uint(p[2 * q + 1]),
                                            __float_as_uint(p[2 * q]), 0x07060302u);
        __builtin_amdgcn_s_setprio(1);
        asum4 = __builtin_amdgcn_mfma_f32_16x16x32_bf16(cv.s8, ones, asum4, 0, 0, 0);
#pragma unroll
        for (int ft = 0; ft < 16; ++ft) {
            int fl = ft * 16 + la;                          // B row = feature index in tile
            int slot = s ^ ((fl >> 1) & 3);
            short8 bfrag = *(const short8*)(tb + fl * 64 + slot * 16);
            acc16[ft] = __builtin_amdgcn_mfma_f32_16x16x32_bf16(cv.s8, bfrag, acc16[ft], 0, 0, 0);
        }
        __builtin_amdgcn_s_setprio(0);
    }

    // D row = (l>>4)*4 + t; asum4[t] = that row's denominator (ones-trick, per-lane)
    float dinv[4];
#pragma unroll
    for (int t = 0; t < 4; ++t)
        dinv[t] = (asum4[t] > 0.f) ? (1.0f / asum4[t]) : 0.f;

#pragma unroll
    for (int ft = 0; ft < 16; ++ft)
#pragma unroll
        for (int t = 0; t < 4; ++t) {
            int grow = rowbase + w * 16 + s * 4 + t;
            if (grow < NN) {
                float v = acc16[ft][t] * dinv[t];
                v = (v > 0.f) ? v : (__expf(v) - 1.f);
                x2[(size_t)grow * FTOT + h * HID + ft * 16 + la] = f2bf(v);
            }
        }
}

// ---------------- GEMM2: split-K x8 -> f32 partials (verified r5) ----------------
__global__ __launch_bounds__(256, 2) void gemm_hc(const unsigned short* __restrict__ A,
                                                  const unsigned short* __restrict__ B,
                                                  float* __restrict__ pk) {
    int w = threadIdx.x >> 6, l = threadIdx.x & 63;
    int lrow = l & 31, kh = l >> 5;
    int q = blockIdx.y;
    int nbase = blockIdx.x * 128 + w * 32;
    int brow = nbase + lrow; if (brow > NN - 1) brow = NN - 1;
    f32x16 acc = (f32x16)0.0f;
    const short8* ap = (const short8*)(A + (size_t)lrow * FTOT + q * 256 + kh * 8);
    const short8* bp = (const short8*)(B + (size_t)brow * FTOT + q * 256 + kh * 8);
#pragma unroll
    for (int kk = 0; kk < 16; ++kk) {
        short8 af = ap[kk * 2];
        short8 bf = bp[kk * 2];
        acc = __builtin_amdgcn_mfma_f32_32x32x16_bf16(af, bf, acc, 0, 0, 0);
    }
    int i = nbase + lrow;
#pragma unroll
    for (int g = 0; g < 4; ++g) {
        int c0 = (g << 3) + (kh << 2);
#pragma unroll
        for (int r = 0; r < 4; ++r)
            pk[((size_t)q * NC + c0 + r) * NPAD + i] = acc[g * 4 + r];
    }
}

__global__ void merge_hc(const float* __restrict__ pk, unsigned short* __restrict__ hct) {
    int i = blockIdx.x * 256 + threadIdx.x;
    int c = blockIdx.y;
    if (i >= NPAD) return;
    float s = 0.f;
#pragma unroll
    for (int q = 0; q < 8; ++q) s += pk[((size_t)q * NC + c) * NPAD + i];
    hct[(size_t)c * NPAD + i] = f2bf(s);
}

// ---------------- classifier attention (verified r14): barrier-free, j-split 8, ones dsum ----------------
__global__ __launch_bounds__(256) void cls_part(
    const unsigned short* __restrict__ hctb,
    const unsigned long long* __restrict__ mask,
    const float* __restrict__ RAc, const float* __restrict__ RBc,
    const float* __restrict__ E2Fc, const float* __restrict__ E2Fcb,
    float* __restrict__ pacc, float* __restrict__ pdsum)
{
    const int w = threadIdx.x >> 6, l = threadIdx.x & 63;
    const int lrow = l & 31, kh = l >> 5;
    const int q = blockIdx.y;
    const int rowbase = blockIdx.x * 128;
    const int myrow = rowbase + w * 32 + lrow;
    const bool act = myrow < NN;
    const float era = exp2f(RAc[myrow]);
    const float erb = exp2f(RBc[myrow]);
    const int JB0 = q * 12, JB1 = (JB0 + 12 < NJB) ? JB0 + 12 : NJB;
    const short8 ones = { (short)0x3F80, (short)0x3F80, (short)0x3F80, (short)0x3F80,
                          (short)0x3F80, (short)0x3F80, (short)0x3F80, (short)0x3F80 };
    f32x16 acc = (f32x16)0.0f;
    f32x16 asum = (f32x16)0.0f;

#pragma unroll 1
    for (int jb = JB0; jb < JB1; ++jb) {
        unsigned long long mword = act ? mask[(size_t)myrow * MSTR + jb] : 0ull;
#pragma unroll
        for (int kk = 0; kk < 4; ++kk) {
            short8 bfrag = *(const short8*)(hctb + (size_t)lrow * NPAD + jb * 64 + (kk * 2 + kh) * 8);
            unsigned int mbyte = (unsigned int)((mword >> (kk * 16 + kh * 8)) & 0xffull);
            int j0 = jb * 64 + kk * 16 + kh * 8;
            f32x4 ea0 = *(const f32x4*)(E2Fc + j0);
            f32x4 ea1 = *(const f32x4*)(E2Fc + j0 + 4);
            f32x4 eb0 = *(const f32x4*)(E2Fcb + j0);
            f32x4 eb1 = *(const f32x4*)(E2Fcb + j0 + 4);
            float p[8];
#pragma unroll
            for (int e = 0; e < 8; ++e) {
                float fe = (e < 4) ? ea0[e & 3] : ea1[e & 3];
                float fb = (e < 4) ? eb0[e & 3] : eb1[e & 3];
                float pe = fmaxf(era * fe, erb * fb);
                p[e] = (mbyte & (1u << e)) ? pe : 0.f;
            }
            union { unsigned int u[4]; short8 s8; } cv;
#pragma unroll
            for (int t = 0; t < 4; ++t)
                cv.u[t] = __builtin_amdgcn_perm(__float_as_uint(p[2 * t + 1]),
                                                __float_as_uint(p[2 * t]), 0x07060302u);
            asum = __builtin_amdgcn_mfma_f32_32x32x16_bf16(cv.s8, ones, asum, 0, 0, 0);
            acc = __builtin_amdgcn_mfma_f32_32x32x16_bf16(cv.s8, bfrag, acc, 0, 0, 0);
        }
    }
#pragma unroll
    for (int g = 0; g < 4; ++g)
#pragma unroll
        for (int rr = 0; rr < 4; ++rr) {
            int i = rowbase + w * 32 + (g << 3) + (kh << 2) + rr;
            pacc[((size_t)q * NPAD + i) * NC + lrow] = acc[g * 4 + rr];
            if (lrow == 0) pdsum[(size_t)q * NPAD + i] = asum[g * 4 + rr];
        }
}

__global__ void cls_merge(const float* __restrict__ pacc, const float* __restrict__ pdsum,
                          float* __restrict__ outp) {
    int i = blockIdx.x * 8 + (threadIdx.x >> 5);
    int c = threadIdx.x & 31;
    if (i >= NN) return;
    float num = 0.f, den = 0.f;
#pragma unroll
    for (int q = 0; q < 8; ++q) {
        num += pacc[((size_t)q * NPAD + i) * NC + c];
        den += pdsum[(size_t)q * NPAD + i];
    }
    outp[(size_t)i * NC + c] = (den > 0.f) ? num / den : 0.f;
}

// ---------------- launcher ----------------
extern "C" void kernel_launch(void* const* d_in, const int* in_sizes, int n_in,
                              void* d_out, int out_size, void* d_ws, size_t ws_size,
                              hipStream_t stream) {
    const float* features = (const float*)d_in[0];
    const int*   adj      = (const int*)d_in[1];
    const float* W0       = (const float*)d_in[2];
    const float* a10      = (const float*)d_in[3];
    const float* a20      = (const float*)d_in[4];
    const float* Wc       = (const float*)d_in[5];
    const float* a1c      = (const float*)d_in[6];
    const float* a2c      = (const float*)d_in[7];
    float* out = (float*)d_out;

    char* p = (char*)d_ws;
    auto alloc = [&](size_t bytes) { char* r = p; p += (bytes + 255) & ~(size_t)255; return r; };
    unsigned long long* mask = (unsigned long long*)alloc((size_t)NN * MSTR * 8);
    unsigned short* Xbf = (unsigned short*)alloc((size_t)NN * DF * 2);
    unsigned short* Wt  = (unsigned short*)alloc((size_t)FTOT * DF * 2);
    unsigned short* Ht  = (unsigned short*)alloc((size_t)FTOT * NPAD * 2);
    unsigned short* x2  = (unsigned short*)alloc((size_t)NN * FTOT * 2);
    unsigned short* Wct = (unsigned short*)alloc((size_t)NC * FTOT * 2);
    unsigned short* hct = (unsigned short*)alloc((size_t)NC * NPAD * 2);
    float* f1  = (float*)alloc((size_t)NH * NPAD * 4);
    float* f2  = (float*)alloc((size_t)NH * NPAD * 4);
    float* RA  = (float*)alloc((size_t)NH * NPAD * 4);
    float* RB  = (float*)alloc((size_t)NH * NPAD * 4);
    float* E2F  = (float*)alloc((size_t)NH * NPAD * 4);
    float* E2Fb = (float*)alloc((size_t)NH * NPAD * 4);
    float* f1c  = (float*)alloc((size_t)NPAD * 4);
    float* f2c  = (float*)alloc((size_t)NPAD * 4);
    float* RAc  = (float*)alloc((size_t)NPAD * 4);
    float* RBc  = (float*)alloc((size_t)NPAD * 4);
    float* E2Fc  = (float*)alloc((size_t)NPAD * 4);
    float* E2Fcb = (float*)alloc((size_t)NPAD * 4);
    // overlays on dead Xbf+Wt (8.26 MB): pkhc 6.16 MB (gemm_hc), then pacc 6.16 MB + pdsum 192 KB (cls)
    float* pkhc  = (float*)Xbf;
    float* pacc  = (float*)Xbf;
    float* pdsum = pacc + (size_t)8 * NPAD * NC;

    pack_bits<<<dim3(3, NN), 256, 0, stream>>>(adj, (unsigned char*)mask);
    cast_x4<<<(NN * DF / 4 + 255) / 256, 256, 0, stream>>>(features, Xbf, NN * DF / 4);
    wt_pack<<<FTOT, 256, 0, stream>>>(W0, Wt);
    wct_pack<<<NC, 256, 0, stream>>>(Wc, Wct);

    gemm_h<<<dim3(NPAD / 128, FTOT / 128), 256, 0, stream>>>(Xbf, Wt, Ht);
    f12_kern<<<dim3((NPAD + 255) / 256, NH), 256, 0, stream>>>(Ht, a10, a20, f1, f2, HID);
    rarb_kern<<<NH, 256, 0, stream>>>(f1, f2, RA, RB, E2F, E2Fb);

    attn_main<<<dim3(94 * NH), 256, 0, stream>>>(Ht, mask, RA, RB, E2F, E2Fb, x2);

    gemm_hc<<<dim3(NPAD / 128, 8), 256, 0, stream>>>(Wct, x2, pkhc);
    merge_hc<<<dim3((NPAD + 255) / 256, NC), 256, 0, stream>>>(pkhc, hct);
    f12_kern<<<dim3((NPAD + 255) / 256, 1), 256, 0, stream>>>(hct, a1c, a2c, f1c, f2c, NC);
    rarb_kern<<<1, 256, 0, stream>>>(f1c, f2c, RAc, RBc, E2Fc, E2Fcb);

    cls_part<<<dim3(47, 8), 256, 0, stream>>>(hct, mask, RAc, RBc, E2Fc, E2Fcb, pacc, pdsum);
    cls_merge<<<750, 256, 0, stream>>>(pacc, pdsum, out);
}

// Round 17
// 418.398 us; speedup vs baseline: 1.0281x; 1.0281x over previous
//
#include <hip/hip_runtime.h>
#include <hip/hip_bf16.h>

#define NN 6000
#define NPAD 6016      // 94*64
#define DF 512
#define HID 256
#define NH 8
#define NC 32
#define FTOT 2048
#define MSTR 96        // u64 words per mask row
#define NJB (NPAD / 64)
#define NJT (NPAD / 32)
#define L2E 1.4426950408889634f

using short8 = __attribute__((ext_vector_type(8))) short;
using f32x16 = __attribute__((ext_vector_type(16))) float;
using f32x4  = __attribute__((ext_vector_type(4))) float;

__device__ __forceinline__ unsigned short f2bf(float f) {
    unsigned int u = __float_as_uint(f);
    return (unsigned short)((u + 0x7fffu + ((u >> 16) & 1u)) >> 16);
}
__device__ __forceinline__ float bf2f(unsigned short s) {
    return __uint_as_float(((unsigned int)s) << 16);
}
// async global->LDS, 16B per lane
__device__ __forceinline__ void gl16(const void* g, void* l) {
    __builtin_amdgcn_global_load_lds(
        (const __attribute__((address_space(1))) unsigned int*)g,
        (__attribute__((address_space(3))) unsigned int*)l, 16, 0, 0);
}

// ---------------- prep kernels (verified r3/r4) ----------------

__global__ void pack_bits(const int* __restrict__ adj, unsigned char* __restrict__ maskb) {
    int row = blockIdx.y;
    int b = blockIdx.x * 256 + threadIdx.x;     // byte index 0..767
    if (b >= 768) return;
    int j0 = b * 8;
    unsigned int v = 0;
    if (j0 + 7 < NN) {
        const int4* p = (const int4*)(adj + (size_t)row * NN + j0);
        int4 a = p[0], c = p[1];
        v = (unsigned)((a.x>0) | ((a.y>0)<<1) | ((a.z>0)<<2) | ((a.w>0)<<3)
          | ((c.x>0)<<4) | ((c.y>0)<<5) | ((c.z>0)<<6) | ((c.w>0)<<7));
    }
    maskb[(size_t)row * 768 + b] = (unsigned char)v;
}

__global__ void cast_x4(const float* __restrict__ x, unsigned short* __restrict__ xb, int n4) {
    int i = blockIdx.x * 256 + threadIdx.x;
    if (i >= n4) return;
    float4 v = ((const float4*)x)[i];
    unsigned long long pk = (unsigned long long)f2bf(v.x)
        | ((unsigned long long)f2bf(v.y) << 16)
        | ((unsigned long long)f2bf(v.z) << 32)
        | ((unsigned long long)f2bf(v.w) << 48);
    ((unsigned long long*)xb)[i] = pk;
}

__global__ void wt_pack(const float* __restrict__ W0, unsigned short* __restrict__ Wt) {
    int fp = blockIdx.x;                 // h*256+f
    int h = fp >> 8, f = fp & 255;
    for (int k = threadIdx.x; k < DF; k += 256)
        Wt[(size_t)fp * DF + k] = f2bf(W0[(((size_t)h * DF + k) << 8) | f]);
}

__global__ void wct_pack(const float* __restrict__ Wc, unsigned short* __restrict__ Wct) {
    int c = blockIdx.x;
    for (int k = threadIdx.x; k < FTOT; k += 256)
        Wct[(size_t)c * FTOT + k] = f2bf(Wc[(size_t)k * NC + c]);
}

// ---------------- GEMM1 (verified r3): Ht[f][i] = sum_k X[i][k] W[k][f] ----------------
__global__ __launch_bounds__(256, 2) void gemm_h(const unsigned short* __restrict__ A,
                                                 const unsigned short* __restrict__ B,
                                                 unsigned short* __restrict__ Ht) {
    __shared__ __align__(16) unsigned short As[128 * 64];
    __shared__ __align__(16) unsigned short Bs[128 * 64];
    const int w = threadIdx.x >> 6, l = threadIdx.x & 63;
    const int lrow = l & 31, kh = l >> 5;
    const int wm = w >> 1, wn = w & 1;
    const int mbase = blockIdx.x * 128, nbase = blockIdx.y * 128;
    const int srcc = (l & 7) ^ (l >> 3);
    f32x16 acc[2][2];
#pragma unroll
    for (int i = 0; i < 2; ++i)
#pragma unroll
        for (int j = 0; j < 2; ++j) acc[i][j] = (f32x16)0.0f;

#pragma unroll 1
    for (int kb = 0; kb < DF / 64; ++kb) {
        __syncthreads();
#pragma unroll
        for (int q = 0; q < 4; ++q) {
            int c = q * 4 + w;
            int r = c * 8 + (l >> 3);
            int arow = mbase + r; if (arow > NN - 1) arow = NN - 1;
            gl16(A + (size_t)arow * DF + kb * 64 + srcc * 8, (char*)As + c * 1024);
            gl16(B + (size_t)(nbase + r) * DF + kb * 64 + srcc * 8, (char*)Bs + c * 1024);
        }
        __syncthreads();
#pragma unroll
        for (int kk = 0; kk < 4; ++kk) {
            short8 av[2], bv[2];
#pragma unroll
            for (int mt = 0; mt < 2; ++mt) {
                int r = wm * 64 + mt * 32 + lrow;
                av[mt] = *(const short8*)((const char*)As + r * 128 + ((((kk << 1) | kh) ^ (r & 7)) << 4));
            }
#pragma unroll
            for (int ft = 0; ft < 2; ++ft) {
                int r = wn * 64 + ft * 32 + lrow;
                bv[ft] = *(const short8*)((const char*)Bs + r * 128 + ((((kk << 1) | kh) ^ (r & 7)) << 4));
            }
#pragma unroll
            for (int mt = 0; mt < 2; ++mt)
#pragma unroll
                for (int ft = 0; ft < 2; ++ft)
                    acc[mt][ft] = __builtin_amdgcn_mfma_f32_32x32x16_bf16(av[mt], bv[ft], acc[mt][ft], 0, 0, 0);
        }
    }
#pragma unroll
    for (int mt = 0; mt < 2; ++mt)
#pragma unroll
        for (int ft = 0; ft < 2; ++ft) {
            size_t n = nbase + wn * 64 + ft * 32 + lrow;
#pragma unroll
            for (int g = 0; g < 4; ++g) {
                int m0 = mbase + wm * 64 + mt * 32 + (g << 3) + (kh << 2);
                unsigned long long pk =
                    (unsigned long long)f2bf(acc[mt][ft][g * 4 + 0]) |
                    ((unsigned long long)f2bf(acc[mt][ft][g * 4 + 1]) << 16) |
                    ((unsigned long long)f2bf(acc[mt][ft][g * 4 + 2]) << 32) |
                    ((unsigned long long)f2bf(acc[mt][ft][g * 4 + 3]) << 48);
                *(unsigned long long*)(Ht + n * NPAD + m0) = pk;
            }
        }
}

// ---------------- f1/f2, pre-scaled by log2e (verified r6) ----------------
__global__ void f12_kern(const unsigned short* __restrict__ Ht, const float* __restrict__ a1,
                         const float* __restrict__ a2, float* __restrict__ f1, float* __restrict__ f2,
                         int fdim) {
    int h = blockIdx.y;
    int i = blockIdx.x * 256 + threadIdx.x;
    if (i >= NPAD) return;
    float s1 = 0.f, s2 = 0.f;
    const unsigned short* base = Ht + (size_t)h * fdim * NPAD + i;
    for (int f = 0; f < fdim; ++f) {
        float v = bf2f(base[(size_t)f * NPAD]);
        s1 = fmaf(v, a1[h * fdim + f], s1);
        s2 = fmaf(v, a2[h * fdim + f], s2);
    }
    f1[(size_t)h * NPAD + i] = s1 * L2E;
    f2[(size_t)h * NPAD + i] = s2 * L2E;
}

// per-head global max -> RA/RB + E2F/E2Fb (verified r14)
__global__ void rarb_kern(const float* __restrict__ f1all, const float* __restrict__ f2all,
                          float* __restrict__ RA, float* __restrict__ RB,
                          float* __restrict__ E2F, float* __restrict__ E2Fb) {
    int h = blockIdx.x;
    __shared__ float red[8];
    const float* f2h = f2all + (size_t)h * NPAD;
    float m = -3.0e38f;
    for (int i = threadIdx.x; i < NN; i += 256) m = fmaxf(m, f2h[i]);
    for (int off = 32; off; off >>= 1) m = fmaxf(m, __shfl_xor(m, off));
    if ((threadIdx.x & 63) == 0) red[threadIdx.x >> 6] = m;
    __syncthreads();
    if (threadIdx.x == 0)
        red[4] = fmaxf(fmaxf(red[0], red[1]), fmaxf(red[2], red[3]));
    __syncthreads();
    float Mh = red[4];
    for (int i = threadIdx.x; i < NPAD; i += 256) {
        float F1 = (i < NN) ? f1all[(size_t)h * NPAD + i] : 0.f;
        float t2 = F1 + Mh;
        float Mi = fmaxf(t2, 0.2f * t2);
        RA[(size_t)h * NPAD + i] = F1 - Mi;
        RB[(size_t)h * NPAD + i] = 0.2f * F1 - Mi;
        float v2 = f2h[i];
        E2F[(size_t)h * NPAD + i] = exp2f(v2);
        E2Fb[(size_t)h * NPAD + i] = exp2f(0.2f * v2);
    }
}

// ---------------- main attention v12: r16 loop + FUSED classifier projection ----------------
// grid 752: h = bid&7 (head->XCD pin), rowblk = bid>>3 (64 rows, 4 waves x 16).
// Loop identical to r16 (triple buffer, conflict-free swizzle, ones-trick dsum).
// Epilogue: normalize+ELU -> bf16 LDS [16r][256f] (row-XOR swizzle) -> 16x16x32 MFMA vs Wct
// -> f32 partials hcp[h][i][c]. x2 / gemm_hc deleted.
__global__ __launch_bounds__(256, 3) void attn_main(
    const unsigned short* __restrict__ Ht,
    const unsigned long long* __restrict__ mask,
    const float* __restrict__ RA, const float* __restrict__ RB,
    const float* __restrict__ E2F, const float* __restrict__ E2Fb,
    const unsigned short* __restrict__ Wct,
    float* __restrict__ hcp)
{
    __shared__ __align__(16) unsigned short htile[3 * 256 * 32];   // 48 KB: 3 x [256 f][32 j]
    const int bid = blockIdx.x;
    const int h = bid & 7;
    const int rowbase = (bid >> 3) * 64;
    const int w = threadIdx.x >> 6, l = threadIdx.x & 63;
    const int la = l & 15;            // A row within wave's 16-row group
    const int s  = l >> 4;            // k-group (8 j's)
    const int rowA = rowbase + w * 16 + la;
    const int rowAc = (rowA < NN) ? rowA : NN - 1;
    const unsigned short* Hh = Ht + (size_t)h * HID * NPAD;
    const float* E2Fh = E2F + (size_t)h * NPAD;
    const float* E2Fbh = E2Fb + (size_t)h * NPAD;
    const float era = exp2f(RA[(size_t)h * NPAD + rowAc]);
    const float erb = exp2f(RB[(size_t)h * NPAD + rowAc]);
    const short8 ones = { (short)0x3F80, (short)0x3F80, (short)0x3F80, (short)0x3F80,
                          (short)0x3F80, (short)0x3F80, (short)0x3F80, (short)0x3F80 };
    f32x4 acc16[16];
    f32x4 asum4 = (f32x4)0.0f;
#pragma unroll
    for (int i = 0; i < 16; ++i) acc16[i] = (f32x4)0.0f;

    // staging: chunk c (0..15) = rows c*16..c*16+15; lane l -> row c*16+(l>>2), stored slot l&3.
    const int segsrc = (l & 3) ^ ((l >> 3) & 3);
    auto STAGE = [&](int buf, int jt) {
#pragma unroll
        for (int q = 0; q < 4; ++q) {
            int c = q * 4 + w;                       // chunk 0..15
            int f = c * 16 + (l >> 2);               // feature row 0..255
            gl16(Hh + (size_t)f * NPAD + jt * 32 + segsrc * 8,
                 (char*)htile + buf * 16384 + c * 1024);
        }
    };

    STAGE(0, 0);
#pragma unroll 1
    for (int jt = 0; jt < NJT; ++jt) {
        if (jt + 1 < NJT) STAGE((jt + 1) % 3, jt + 1);     // depth-1 prefetch (4 gl16, static)
        asm volatile("s_waitcnt vmcnt(4)" ::: "memory");   // own S(jt) retired; prefetch in flight
        __builtin_amdgcn_sched_barrier(0);
        __builtin_amdgcn_s_barrier();                      // publish tile jt (non-draining)
        __builtin_amdgcn_sched_barrier(0);
        const char* tb = (const char*)htile + (jt % 3) * 16384;
        unsigned int mwrd = ((const unsigned int*)mask)[(size_t)rowAc * 192 + jt];
        unsigned int mbyte = (mwrd >> (s * 8)) & 0xffu;
        int j0 = jt * 32 + s * 8;
        f32x4 ea0 = *(const f32x4*)(E2Fh + j0);
        f32x4 ea1 = *(const f32x4*)(E2Fh + j0 + 4);
        f32x4 eb0 = *(const f32x4*)(E2Fbh + j0);
        f32x4 eb1 = *(const f32x4*)(E2Fbh + j0 + 4);
        float p[8];
#pragma unroll
        for (int e = 0; e < 8; ++e) {
            float fe = (e < 4) ? ea0[e & 3] : ea1[e & 3];
            float fb = (e < 4) ? eb0[e & 3] : eb1[e & 3];
            float pe = fmaxf(era * fe, erb * fb);          // == exp2(max(ra+f, rb+0.2f))
            p[e] = (mbyte & (1u << e)) ? pe : 0.f;
        }
        union { unsigned int u[4]; short8 s8; } cv;
#pragma unroll
        for (int q = 0; q < 4; ++q)
            cv.u[q] = __builtin_amdgcn_perm(__float_as_uint(p[2 * q + 1]),
                                            __float_as_uint(p[2 * q]), 0x07060302u);
        __builtin_amdgcn_s_setprio(1);
        asum4 = __builtin_amdgcn_mfma_f32_16x16x32_bf16(cv.s8, ones, asum4, 0, 0, 0);
#pragma unroll
        for (int ft = 0; ft < 16; ++ft) {
            int fl = ft * 16 + la;                          // B row = feature index in tile
            int slot = s ^ ((fl >> 1) & 3);
            short8 bfrag = *(const short8*)(tb + fl * 64 + slot * 16);
            acc16[ft] = __builtin_amdgcn_mfma_f32_16x16x32_bf16(cv.s8, bfrag, acc16[ft], 0, 0, 0);
        }
        __builtin_amdgcn_s_setprio(0);
    }

    // D row = (l>>4)*4 + t; asum4[t] = that row's denominator (ones-trick, per-lane)
    float dinv[4];
#pragma unroll
    for (int t = 0; t < 4; ++t)
        dinv[t] = (asum4[t] > 0.f) ? (1.0f / asum4[t]) : 0.f;

    // ---- fused classifier: v = elu(acc/dsum) -> LDS [16r][256f] swizzled -> MFMA vs Wct ----
    __syncthreads();                                 // all waves done reading tiles
    unsigned short* vlds = htile + w * 4096;         // private 8 KB region per wave
#pragma unroll
    for (int ft = 0; ft < 16; ++ft)
#pragma unroll
        for (int t = 0; t < 4; ++t) {
            int r = s * 4 + t;                       // wave-local node row 0..15
            float v = acc16[ft][t] * dinv[t];
            v = (v > 0.f) ? v : (__expf(v) - 1.f);
            int f = ft * 16 + la;
            int byt = r * 512 + ((f * 2) ^ ((r & 7) << 4));
            *(unsigned short*)((char*)vlds + byt) = f2bf(v);
        }
    f32x4 cacc0 = (f32x4)0.0f, cacc1 = (f32x4)0.0f;
#pragma unroll
    for (int kk = 0; kk < 8; ++kk) {
        // A: row = la, k = kk*32 + s*8 + e (r15-verified 16x16 A layout)
        short8 afrag = *(const short8*)((char*)vlds + la * 512 + ((kk * 64 + s * 16) ^ ((la & 7) << 4)));
        short8 b0 = *(const short8*)(Wct + (size_t)la * FTOT + h * HID + kk * 32 + s * 8);
        short8 b1 = *(const short8*)(Wct + (size_t)(16 + la) * FTOT + h * HID + kk * 32 + s * 8);
        cacc0 = __builtin_amdgcn_mfma_f32_16x16x32_bf16(afrag, b0, cacc0, 0, 0, 0);
        cacc1 = __builtin_amdgcn_mfma_f32_16x16x32_bf16(afrag, b1, cacc1, 0, 0, 0);
    }
    // D: col = la (class), row = s*4+t (node) -> hcp[h][i][c]
#pragma unroll
    for (int t = 0; t < 4; ++t) {
        int grow = rowbase + w * 16 + s * 4 + t;
        if (grow < NN) {
            hcp[((size_t)h * NPAD + grow) * NC + la] = cacc0[t];
            hcp[((size_t)h * NPAD + grow) * NC + 16 + la] = cacc1[t];
        }
    }
}

// hct[c][i] = bf16( sum_h hcp[h][i][c] ); pads zeroed (no poison downstream)
__global__ void merge_hcp(const float* __restrict__ hcp, unsigned short* __restrict__ hct) {
    int idx = blockIdx.x * 256 + threadIdx.x;        // (i*32 + c)
    int i = idx >> 5, c = idx & 31;
    if (i >= NPAD) return;
    float sum = 0.f;
    if (i < NN) {
#pragma unroll
        for (int hh = 0; hh < NH; ++hh) sum += hcp[((size_t)hh * NPAD + i) * NC + c];
    }
    hct[(size_t)c * NPAD + i] = f2bf(sum);
}

// ---------------- classifier attention (verified r14): barrier-free, j-split 8, ones dsum ----------------
__global__ __launch_bounds__(256) void cls_part(
    const unsigned short* __restrict__ hctb,
    const unsigned long long* __restrict__ mask,
    const float* __restrict__ RAc, const float* __restrict__ RBc,
    const float* __restrict__ E2Fc, const float* __restrict__ E2Fcb,
    float* __restrict__ pacc, float* __restrict__ pdsum)
{
    const int w = threadIdx.x >> 6, l = threadIdx.x & 63;
    const int lrow = l & 31, kh = l >> 5;
    const int q = blockIdx.y;
    const int rowbase = blockIdx.x * 128;
    const int myrow = rowbase + w * 32 + lrow;
    const bool act = myrow < NN;
    const float era = exp2f(RAc[myrow]);
    const float erb = exp2f(RBc[myrow]);
    const int JB0 = q * 12, JB1 = (JB0 + 12 < NJB) ? JB0 + 12 : NJB;
    const short8 ones = { (short)0x3F80, (short)0x3F80, (short)0x3F80, (short)0x3F80,
                          (short)0x3F80, (short)0x3F80, (short)0x3F80, (short)0x3F80 };
    f32x16 acc = (f32x16)0.0f;
    f32x16 asum = (f32x16)0.0f;

#pragma unroll 1
    for (int jb = JB0; jb < JB1; ++jb) {
        unsigned long long mword = act ? mask[(size_t)myrow * MSTR + jb] : 0ull;
#pragma unroll
        for (int kk = 0; kk < 4; ++kk) {
            short8 bfrag = *(const short8*)(hctb + (size_t)lrow * NPAD + jb * 64 + (kk * 2 + kh) * 8);
            unsigned int mbyte = (unsigned int)((mword >> (kk * 16 + kh * 8)) & 0xffull);
            int j0 = jb * 64 + kk * 16 + kh * 8;
            f32x4 ea0 = *(const f32x4*)(E2Fc + j0);
            f32x4 ea1 = *(const f32x4*)(E2Fc + j0 + 4);
            f32x4 eb0 = *(const f32x4*)(E2Fcb + j0);
            f32x4 eb1 = *(const f32x4*)(E2Fcb + j0 + 4);
            float p[8];
#pragma unroll
            for (int e = 0; e < 8; ++e) {
                float fe = (e < 4) ? ea0[e & 3] : ea1[e & 3];
                float fb = (e < 4) ? eb0[e & 3] : eb1[e & 3];
                float pe = fmaxf(era * fe, erb * fb);
                p[e] = (mbyte & (1u << e)) ? pe : 0.f;
            }
            union { unsigned int u[4]; short8 s8; } cv;
#pragma unroll
            for (int t = 0; t < 4; ++t)
                cv.u[t] = __builtin_amdgcn_perm(__float_as_uint(p[2 * t + 1]),
                                                __float_as_uint(p[2 * t]), 0x07060302u);
            asum = __builtin_amdgcn_mfma_f32_32x32x16_bf16(cv.s8, ones, asum, 0, 0, 0);
            acc = __builtin_amdgcn_mfma_f32_32x32x16_bf16(cv.s8, bfrag, acc, 0, 0, 0);
        }
    }
#pragma unroll
    for (int g = 0; g < 4; ++g)
#pragma unroll
        for (int rr = 0; rr < 4; ++rr) {
            int i = rowbase + w * 32 + (g << 3) + (kh << 2) + rr;
            pacc[((size_t)q * NPAD + i) * NC + lrow] = acc[g * 4 + rr];
            if (lrow == 0) pdsum[(size_t)q * NPAD + i] = asum[g * 4 + rr];
        }
}

__global__ void cls_merge(const float* __restrict__ pacc, const float* __restrict__ pdsum,
                          float* __restrict__ outp) {
    int i = blockIdx.x * 8 + (threadIdx.x >> 5);
    int c = threadIdx.x & 31;
    if (i >= NN) return;
    float num = 0.f, den = 0.f;
#pragma unroll
    for (int q = 0; q < 8; ++q) {
        num += pacc[((size_t)q * NPAD + i) * NC + c];
        den += pdsum[(size_t)q * NPAD + i];
    }
    outp[(size_t)i * NC + c] = (den > 0.f) ? num / den : 0.f;
}

// ---------------- launcher ----------------
extern "C" void kernel_launch(void* const* d_in, const int* in_sizes, int n_in,
                              void* d_out, int out_size, void* d_ws, size_t ws_size,
                              hipStream_t stream) {
    const float* features = (const float*)d_in[0];
    const int*   adj      = (const int*)d_in[1];
    const float* W0       = (const float*)d_in[2];
    const float* a10      = (const float*)d_in[3];
    const float* a20      = (const float*)d_in[4];
    const float* Wc       = (const float*)d_in[5];
    const float* a1c      = (const float*)d_in[6];
    const float* a2c      = (const float*)d_in[7];
    float* out = (float*)d_out;

    char* p = (char*)d_ws;
    auto alloc = [&](size_t bytes) { char* r = p; p += (bytes + 255) & ~(size_t)255; return r; };
    unsigned long long* mask = (unsigned long long*)alloc((size_t)NN * MSTR * 8);
    unsigned short* Xbf = (unsigned short*)alloc((size_t)NN * DF * 2);
    unsigned short* Wt  = (unsigned short*)alloc((size_t)FTOT * DF * 2);
    unsigned short* Ht  = (unsigned short*)alloc((size_t)FTOT * NPAD * 2);
    unsigned short* Wct = (unsigned short*)alloc((size_t)NC * FTOT * 2);
    unsigned short* hct = (unsigned short*)alloc((size_t)NC * NPAD * 2);
    float* f1  = (float*)alloc((size_t)NH * NPAD * 4);
    float* f2  = (float*)alloc((size_t)NH * NPAD * 4);
    float* RA  = (float*)alloc((size_t)NH * NPAD * 4);
    float* RB  = (float*)alloc((size_t)NH * NPAD * 4);
    float* E2F  = (float*)alloc((size_t)NH * NPAD * 4);
    float* E2Fb = (float*)alloc((size_t)NH * NPAD * 4);
    float* f1c  = (float*)alloc((size_t)NPAD * 4);
    float* f2c  = (float*)alloc((size_t)NPAD * 4);
    float* RAc  = (float*)alloc((size_t)NPAD * 4);
    float* RBc  = (float*)alloc((size_t)NPAD * 4);
    float* E2Fc  = (float*)alloc((size_t)NPAD * 4);
    float* E2Fcb = (float*)alloc((size_t)NPAD * 4);
    // overlays on dead Xbf+Wt (8.26 MB):
    //   hcp [8][NPAD][32] f32 = 6.16 MB (attn writes, merge_hcp reads)
    //   then pacc 6.16 MB + pdsum 192 KB (cls_part, after hcp is dead)
    float* hcp   = (float*)Xbf;
    float* pacc  = (float*)Xbf;
    float* pdsum = pacc + (size_t)8 * NPAD * NC;

    pack_bits<<<dim3(3, NN), 256, 0, stream>>>(adj, (unsigned char*)mask);
    cast_x4<<<(NN * DF / 4 + 255) / 256, 256, 0, stream>>>(features, Xbf, NN * DF / 4);
    wt_pack<<<FTOT, 256, 0, stream>>>(W0, Wt);
    wct_pack<<<NC, 256, 0, stream>>>(Wc, Wct);

    gemm_h<<<dim3(NPAD / 128, FTOT / 128), 256, 0, stream>>>(Xbf, Wt, Ht);
    f12_kern<<<dim3((NPAD + 255) / 256, NH), 256, 0, stream>>>(Ht, a10, a20, f1, f2, HID);
    rarb_kern<<<NH, 256, 0, stream>>>(f1, f2, RA, RB, E2F, E2Fb);

    attn_main<<<dim3(94 * NH), 256, 0, stream>>>(Ht, mask, RA, RB, E2F, E2Fb, Wct, hcp);

    merge_hcp<<<(NPAD * NC + 255) / 256, 256, 0, stream>>>(hcp, hct);
    f12_kern<<<dim3((NPAD + 255) / 256, 1), 256, 0, stream>>>(hct, a1c, a2c, f1c, f2c, NC);
    rarb_kern<<<1, 256, 0, stream>>>(f1c, f2c, RAc, RBc, E2Fc, E2Fcb);

    cls_part<<<dim3(47, 8), 256, 0, stream>>>(hct, mask, RAc, RBc, E2Fc, E2Fcb, pacc, pdsum);
    cls_merge<<<750, 256, 0, stream>>>(pacc, pdsum, out);
}

// Round 18
// 407.971 us; speedup vs baseline: 1.0543x; 1.0256x over previous
//
#include <hip/hip_runtime.h>
#include <hip/hip_bf16.h>

#define NN 6000
#define NPAD 6016      // 94*64
#define DF 512
#define HID 256
#define NH 8
#define NC 32
#define FTOT 2048
#define MSTR 96        // u64 words per mask row
#define NJB (NPAD / 64)
#define NJT (NPAD / 32)
#define L2E 1.4426950408889634f

using short8 = __attribute__((ext_vector_type(8))) short;
using f32x16 = __attribute__((ext_vector_type(16))) float;
using f32x4  = __attribute__((ext_vector_type(4))) float;

__device__ __forceinline__ unsigned short f2bf(float f) {
    unsigned int u = __float_as_uint(f);
    return (unsigned short)((u + 0x7fffu + ((u >> 16) & 1u)) >> 16);
}
__device__ __forceinline__ float bf2f(unsigned short s) {
    return __uint_as_float(((unsigned int)s) << 16);
}
// async global->LDS, 16B per lane
__device__ __forceinline__ void gl16(const void* g, void* l) {
    __builtin_amdgcn_global_load_lds(
        (const __attribute__((address_space(1))) unsigned int*)g,
        (__attribute__((address_space(3))) unsigned int*)l, 16, 0, 0);
}

// ---------------- fused prep (bodies verified r3/r4; pure re-indexing) ----------------
// blocks [0,18000): pack_bits; [18000,21000): cast_x4; [21000,23048): wt_pack; [23048,23080): wct_pack
#define NB_PACK 18000
#define NB_CAST 3000
#define NB_WT   2048
#define NB_WCT  32
__global__ void prep_all(const int* __restrict__ adj, unsigned char* __restrict__ maskb,
                         const float* __restrict__ x, unsigned short* __restrict__ xb,
                         const float* __restrict__ W0, unsigned short* __restrict__ Wt,
                         const float* __restrict__ Wc, unsigned short* __restrict__ Wct) {
    int bid = blockIdx.x;
    if (bid < NB_PACK) {
        int row = bid / 3, xbq = bid % 3;
        int b = xbq * 256 + threadIdx.x;
        if (b >= 768) return;
        int j0 = b * 8;
        unsigned int v = 0;
        if (j0 + 7 < NN) {
            const int4* p = (const int4*)(adj + (size_t)row * NN + j0);
            int4 a = p[0], c = p[1];
            v = (unsigned)((a.x>0) | ((a.y>0)<<1) | ((a.z>0)<<2) | ((a.w>0)<<3)
              | ((c.x>0)<<4) | ((c.y>0)<<5) | ((c.z>0)<<6) | ((c.w>0)<<7));
        }
        maskb[(size_t)row * 768 + b] = (unsigned char)v;
    } else if (bid < NB_PACK + NB_CAST) {
        int i = (bid - NB_PACK) * 256 + threadIdx.x;   // i < 768000 exactly
        float4 v = ((const float4*)x)[i];
        unsigned long long pk = (unsigned long long)f2bf(v.x)
            | ((unsigned long long)f2bf(v.y) << 16)
            | ((unsigned long long)f2bf(v.z) << 32)
            | ((unsigned long long)f2bf(v.w) << 48);
        ((unsigned long long*)xb)[i] = pk;
    } else if (bid < NB_PACK + NB_CAST + NB_WT) {
        int fp = bid - NB_PACK - NB_CAST;              // h*256+f
        int h = fp >> 8, f = fp & 255;
        for (int k = threadIdx.x; k < DF; k += 256)
            Wt[(size_t)fp * DF + k] = f2bf(W0[(((size_t)h * DF + k) << 8) | f]);
    } else {
        int c = bid - NB_PACK - NB_CAST - NB_WT;
        for (int k = threadIdx.x; k < FTOT; k += 256)
            Wct[(size_t)c * FTOT + k] = f2bf(Wc[(size_t)k * NC + c]);
    }
}

// ---------------- GEMM1 (verified r3): Ht[f][i] = sum_k X[i][k] W[k][f] ----------------
__global__ __launch_bounds__(256, 2) void gemm_h(const unsigned short* __restrict__ A,
                                                 const unsigned short* __restrict__ B,
                                                 unsigned short* __restrict__ Ht) {
    __shared__ __align__(16) unsigned short As[128 * 64];
    __shared__ __align__(16) unsigned short Bs[128 * 64];
    const int w = threadIdx.x >> 6, l = threadIdx.x & 63;
    const int lrow = l & 31, kh = l >> 5;
    const int wm = w >> 1, wn = w & 1;
    const int mbase = blockIdx.x * 128, nbase = blockIdx.y * 128;
    const int srcc = (l & 7) ^ (l >> 3);
    f32x16 acc[2][2];
#pragma unroll
    for (int i = 0; i < 2; ++i)
#pragma unroll
        for (int j = 0; j < 2; ++j) acc[i][j] = (f32x16)0.0f;

#pragma unroll 1
    for (int kb = 0; kb < DF / 64; ++kb) {
        __syncthreads();
#pragma unroll
        for (int q = 0; q < 4; ++q) {
            int c = q * 4 + w;
            int r = c * 8 + (l >> 3);
            int arow = mbase + r; if (arow > NN - 1) arow = NN - 1;
            gl16(A + (size_t)arow * DF + kb * 64 + srcc * 8, (char*)As + c * 1024);
            gl16(B + (size_t)(nbase + r) * DF + kb * 64 + srcc * 8, (char*)Bs + c * 1024);
        }
        __syncthreads();
#pragma unroll
        for (int kk = 0; kk < 4; ++kk) {
            short8 av[2], bv[2];
#pragma unroll
            for (int mt = 0; mt < 2; ++mt) {
                int r = wm * 64 + mt * 32 + lrow;
                av[mt] = *(const short8*)((const char*)As + r * 128 + ((((kk << 1) | kh) ^ (r & 7)) << 4));
            }
#pragma unroll
            for (int ft = 0; ft < 2; ++ft) {
                int r = wn * 64 + ft * 32 + lrow;
                bv[ft] = *(const short8*)((const char*)Bs + r * 128 + ((((kk << 1) | kh) ^ (r & 7)) << 4));
            }
#pragma unroll
            for (int mt = 0; mt < 2; ++mt)
#pragma unroll
                for (int ft = 0; ft < 2; ++ft)
                    acc[mt][ft] = __builtin_amdgcn_mfma_f32_32x32x16_bf16(av[mt], bv[ft], acc[mt][ft], 0, 0, 0);
        }
    }
#pragma unroll
    for (int mt = 0; mt < 2; ++mt)
#pragma unroll
        for (int ft = 0; ft < 2; ++ft) {
            size_t n = nbase + wn * 64 + ft * 32 + lrow;
#pragma unroll
            for (int g = 0; g < 4; ++g) {
                int m0 = mbase + wm * 64 + mt * 32 + (g << 3) + (kh << 2);
                unsigned long long pk =
                    (unsigned long long)f2bf(acc[mt][ft][g * 4 + 0]) |
                    ((unsigned long long)f2bf(acc[mt][ft][g * 4 + 1]) << 16) |
                    ((unsigned long long)f2bf(acc[mt][ft][g * 4 + 2]) << 32) |
                    ((unsigned long long)f2bf(acc[mt][ft][g * 4 + 3]) << 48);
                *(unsigned long long*)(Ht + n * NPAD + m0) = pk;
            }
        }
}

// ---------------- f1/f2 split over z f-chunks -> partials [z][nh][NPAD] (L2E distributes) ----------------
__global__ void f12s_kern(const unsigned short* __restrict__ Ht, const float* __restrict__ a1,
                          const float* __restrict__ a2, float* __restrict__ f1p, float* __restrict__ f2p,
                          int fdim, int nz) {
    int h = blockIdx.y, z = blockIdx.z, nh = gridDim.y;
    int i = blockIdx.x * 256 + threadIdx.x;
    if (i >= NPAD) return;
    int fc = fdim / nz, f0 = z * fc;
    float s1 = 0.f, s2 = 0.f;
    const unsigned short* base = Ht + ((size_t)h * fdim + f0) * NPAD + i;
    for (int f = 0; f < fc; ++f) {
        float v = bf2f(base[(size_t)f * NPAD]);
        s1 = fmaf(v, a1[h * fdim + f0 + f], s1);
        s2 = fmaf(v, a2[h * fdim + f0 + f], s2);
    }
    f1p[((size_t)z * nh + h) * NPAD + i] = s1 * L2E;
    f2p[((size_t)z * nh + h) * NPAD + i] = s2 * L2E;
}

// per-head: merge z-partials (fixed order, deterministic), global max -> RA/RB + E2F/E2Fb
// (r14-verified math; pass1 stores merged f2 into the z=0 slice)
__global__ void rarb_kern(float* __restrict__ f1p, float* __restrict__ f2p,
                          float* __restrict__ RA, float* __restrict__ RB,
                          float* __restrict__ E2F, float* __restrict__ E2Fb, int nz) {
    int h = blockIdx.x, nh = gridDim.x;
    __shared__ float red[8];
    float m = -3.0e38f;
    for (int i = threadIdx.x; i < NPAD; i += 256) {
        float v = 0.f;
        for (int z = 0; z < nz; ++z) v += f2p[((size_t)z * nh + h) * NPAD + i];
        f2p[(size_t)h * NPAD + i] = v;                 // merged (z=0 slice)
        if (i < NN) m = fmaxf(m, v);
    }
    for (int off = 32; off; off >>= 1) m = fmaxf(m, __shfl_xor(m, off));
    if ((threadIdx.x & 63) == 0) red[threadIdx.x >> 6] = m;
    __syncthreads();
    if (threadIdx.x == 0)
        red[4] = fmaxf(fmaxf(red[0], red[1]), fmaxf(red[2], red[3]));
    __syncthreads();
    float Mh = red[4];
    for (int i = threadIdx.x; i < NPAD; i += 256) {
        float F1 = 0.f;
        for (int z = 0; z < nz; ++z) F1 += f1p[((size_t)z * nh + h) * NPAD + i];
        if (i >= NN) F1 = 0.f;
        float t2 = F1 + Mh;
        float Mi = fmaxf(t2, 0.2f * t2);
        RA[(size_t)h * NPAD + i] = F1 - Mi;
        RB[(size_t)h * NPAD + i] = 0.2f * F1 - Mi;
        float v2 = f2p[(size_t)h * NPAD + i];
        E2F[(size_t)h * NPAD + i] = exp2f(v2);
        E2Fb[(size_t)h * NPAD + i] = exp2f(0.2f * v2);
    }
}

// ---------------- main attention (byte-identical to r17 passing version) ----------------
__global__ __launch_bounds__(256, 3) void attn_main(
    const unsigned short* __restrict__ Ht,
    const unsigned long long* __restrict__ mask,
    const float* __restrict__ RA, const float* __restrict__ RB,
    const float* __restrict__ E2F, const float* __restrict__ E2Fb,
    const unsigned short* __restrict__ Wct,
    float* __restrict__ hcp)
{
    __shared__ __align__(16) unsigned short htile[3 * 256 * 32];   // 48 KB: 3 x [256 f][32 j]
    const int bid = blockIdx.x;
    const int h = bid & 7;
    const int rowbase = (bid >> 3) * 64;
    const int w = threadIdx.x >> 6, l = threadIdx.x & 63;
    const int la = l & 15;            // A row within wave's 16-row group
    const int s  = l >> 4;            // k-group (8 j's)
    const int rowA = rowbase + w * 16 + la;
    const int rowAc = (rowA < NN) ? rowA : NN - 1;
    const unsigned short* Hh = Ht + (size_t)h * HID * NPAD;
    const float* E2Fh = E2F + (size_t)h * NPAD;
    const float* E2Fbh = E2Fb + (size_t)h * NPAD;
    const float era = exp2f(RA[(size_t)h * NPAD + rowAc]);
    const float erb = exp2f(RB[(size_t)h * NPAD + rowAc]);
    const short8 ones = { (short)0x3F80, (short)0x3F80, (short)0x3F80, (short)0x3F80,
                          (short)0x3F80, (short)0x3F80, (short)0x3F80, (short)0x3F80 };
    f32x4 acc16[16];
    f32x4 asum4 = (f32x4)0.0f;
#pragma unroll
    for (int i = 0; i < 16; ++i) acc16[i] = (f32x4)0.0f;

    const int segsrc = (l & 3) ^ ((l >> 3) & 3);
    auto STAGE = [&](int buf, int jt) {
#pragma unroll
        for (int q = 0; q < 4; ++q) {
            int c = q * 4 + w;                       // chunk 0..15
            int f = c * 16 + (l >> 2);               // feature row 0..255
            gl16(Hh + (size_t)f * NPAD + jt * 32 + segsrc * 8,
                 (char*)htile + buf * 16384 + c * 1024);
        }
    };

    STAGE(0, 0);
#pragma unroll 1
    for (int jt = 0; jt < NJT; ++jt) {
        if (jt + 1 < NJT) STAGE((jt + 1) % 3, jt + 1);     // depth-1 prefetch (4 gl16, static)
        asm volatile("s_waitcnt vmcnt(4)" ::: "memory");   // own S(jt) retired; prefetch in flight
        __builtin_amdgcn_sched_barrier(0);
        __builtin_amdgcn_s_barrier();                      // publish tile jt (non-draining)
        __builtin_amdgcn_sched_barrier(0);
        const char* tb = (const char*)htile + (jt % 3) * 16384;
        unsigned int mwrd = ((const unsigned int*)mask)[(size_t)rowAc * 192 + jt];
        unsigned int mbyte = (mwrd >> (s * 8)) & 0xffu;
        int j0 = jt * 32 + s * 8;
        f32x4 ea0 = *(const f32x4*)(E2Fh + j0);
        f32x4 ea1 = *(const f32x4*)(E2Fh + j0 + 4);
        f32x4 eb0 = *(const f32x4*)(E2Fbh + j0);
        f32x4 eb1 = *(const f32x4*)(E2Fbh + j0 + 4);
        float p[8];
#pragma unroll
        for (int e = 0; e < 8; ++e) {
            float fe = (e < 4) ? ea0[e & 3] : ea1[e & 3];
            float fb = (e < 4) ? eb0[e & 3] : eb1[e & 3];
            float pe = fmaxf(era * fe, erb * fb);          // == exp2(max(ra+f, rb+0.2f))
            p[e] = (mbyte & (1u << e)) ? pe : 0.f;
        }
        union { unsigned int u[4]; short8 s8; } cv;
#pragma unroll
        for (int q = 0; q < 4; ++q)
            cv.u[q] = __builtin_amdgcn_perm(__float_as_uint(p[2 * q + 1]),
                                            __float_as_uint(p[2 * q]), 0x07060302u);
        __builtin_amdgcn_s_setprio(1);
        asum4 = __builtin_amdgcn_mfma_f32_16x16x32_bf16(cv.s8, ones, asum4, 0, 0, 0);
#pragma unroll
        for (int ft = 0; ft < 16; ++ft) {
            int fl = ft * 16 + la;                          // B row = feature index in tile
            int slot = s ^ ((fl >> 1) & 3);
            short8 bfrag = *(const short8*)(tb + fl * 64 + slot * 16);
            acc16[ft] = __builtin_amdgcn_mfma_f32_16x16x32_bf16(cv.s8, bfrag, acc16[ft], 0, 0, 0);
        }
        __builtin_amdgcn_s_setprio(0);
    }

    // D row = (l>>4)*4 + t; asum4[t] = that row's denominator (ones-trick, per-lane)
    float dinv[4];
#pragma unroll
    for (int t = 0; t < 4; ++t)
        dinv[t] = (asum4[t] > 0.f) ? (1.0f / asum4[t]) : 0.f;

    // ---- fused classifier: v = elu(acc/dsum) -> LDS [16r][256f] swizzled -> MFMA vs Wct ----
    __syncthreads();                                 // all waves done reading tiles
    unsigned short* vlds = htile + w * 4096;         // private 8 KB region per wave
#pragma unroll
    for (int ft = 0; ft < 16; ++ft)
#pragma unroll
        for (int t = 0; t < 4; ++t) {
            int r = s * 4 + t;                       // wave-local node row 0..15
            float v = acc16[ft][t] * dinv[t];
            v = (v > 0.f) ? v : (__expf(v) - 1.f);
            int f = ft * 16 + la;
            int byt = r * 512 + ((f * 2) ^ ((r & 7) << 4));
            *(unsigned short*)((char*)vlds + byt) = f2bf(v);
        }
    f32x4 cacc0 = (f32x4)0.0f, cacc1 = (f32x4)0.0f;
#pragma unroll
    for (int kk = 0; kk < 8; ++kk) {
        short8 afrag = *(const short8*)((char*)vlds + la * 512 + ((kk * 64 + s * 16) ^ ((la & 7) << 4)));
        short8 b0 = *(const short8*)(Wct + (size_t)la * FTOT + h * HID + kk * 32 + s * 8);
        short8 b1 = *(const short8*)(Wct + (size_t)(16 + la) * FTOT + h * HID + kk * 32 + s * 8);
        cacc0 = __builtin_amdgcn_mfma_f32_16x16x32_bf16(afrag, b0, cacc0, 0, 0, 0);
        cacc1 = __builtin_amdgcn_mfma_f32_16x16x32_bf16(afrag, b1, cacc1, 0, 0, 0);
    }
#pragma unroll
    for (int t = 0; t < 4; ++t) {
        int grow = rowbase + w * 16 + s * 4 + t;
        if (grow < NN) {
            hcp[((size_t)h * NPAD + grow) * NC + la] = cacc0[t];
            hcp[((size_t)h * NPAD + grow) * NC + 16 + la] = cacc1[t];
        }
    }
}

// hct[c][i] = bf16( sum_h hcp[h][i][c] ); pads zeroed (no poison downstream)
__global__ void merge_hcp(const float* __restrict__ hcp, unsigned short* __restrict__ hct) {
    int idx = blockIdx.x * 256 + threadIdx.x;        // (i*32 + c)
    int i = idx >> 5, c = idx & 31;
    if (i >= NPAD) return;
    float sum = 0.f;
    if (i < NN) {
#pragma unroll
        for (int hh = 0; hh < NH; ++hh) sum += hcp[((size_t)hh * NPAD + i) * NC + c];
    }
    hct[(size_t)c * NPAD + i] = f2bf(sum);
}

// ---------------- classifier attention (verified r14): barrier-free, j-split 8, ones dsum ----------------
__global__ __launch_bounds__(256) void cls_part(
    const unsigned short* __restrict__ hctb,
    const unsigned long long* __restrict__ mask,
    const float* __restrict__ RAc, const float* __restrict__ RBc,
    const float* __restrict__ E2Fc, const float* __restrict__ E2Fcb,
    float* __restrict__ pacc, float* __restrict__ pdsum)
{
    const int w = threadIdx.x >> 6, l = threadIdx.x & 63;
    const int lrow = l & 31, kh = l >> 5;
    const int q = blockIdx.y;
    const int rowbase = blockIdx.x * 128;
    const int myrow = rowbase + w * 32 + lrow;
    const bool act = myrow < NN;
    const float era = exp2f(RAc[myrow]);
    const float erb = exp2f(RBc[myrow]);
    const int JB0 = q * 12, JB1 = (JB0 + 12 < NJB) ? JB0 + 12 : NJB;
    const short8 ones = { (short)0x3F80, (short)0x3F80, (short)0x3F80, (short)0x3F80,
                          (short)0x3F80, (short)0x3F80, (short)0x3F80, (short)0x3F80 };
    f32x16 acc = (f32x16)0.0f;
    f32x16 asum = (f32x16)0.0f;

#pragma unroll 1
    for (int jb = JB0; jb < JB1; ++jb) {
        unsigned long long mword = act ? mask[(size_t)myrow * MSTR + jb] : 0ull;
#pragma unroll
        for (int kk = 0; kk < 4; ++kk) {
            short8 bfrag = *(const short8*)(hctb + (size_t)lrow * NPAD + jb * 64 + (kk * 2 + kh) * 8);
            unsigned int mbyte = (unsigned int)((mword >> (kk * 16 + kh * 8)) & 0xffull);
            int j0 = jb * 64 + kk * 16 + kh * 8;
            f32x4 ea0 = *(const f32x4*)(E2Fc + j0);
            f32x4 ea1 = *(const f32x4*)(E2Fc + j0 + 4);
            f32x4 eb0 = *(const f32x4*)(E2Fcb + j0);
            f32x4 eb1 = *(const f32x4*)(E2Fcb + j0 + 4);
            float p[8];
#pragma unroll
            for (int e = 0; e < 8; ++e) {
                float fe = (e < 4) ? ea0[e & 3] : ea1[e & 3];
                float fb = (e < 4) ? eb0[e & 3] : eb1[e & 3];
                float pe = fmaxf(era * fe, erb * fb);
                p[e] = (mbyte & (1u << e)) ? pe : 0.f;
            }
            union { unsigned int u[4]; short8 s8; } cv;
#pragma unroll
            for (int t = 0; t < 4; ++t)
                cv.u[t] = __builtin_amdgcn_perm(__float_as_uint(p[2 * t + 1]),
                                                __float_as_uint(p[2 * t]), 0x07060302u);
            asum = __builtin_amdgcn_mfma_f32_32x32x16_bf16(cv.s8, ones, asum, 0, 0, 0);
            acc = __builtin_amdgcn_mfma_f32_32x32x16_bf16(cv.s8, bfrag, acc, 0, 0, 0);
        }
    }
#pragma unroll
    for (int g = 0; g < 4; ++g)
#pragma unroll
        for (int rr = 0; rr < 4; ++rr) {
            int i = rowbase + w * 32 + (g << 3) + (kh << 2) + rr;
            pacc[((size_t)q * NPAD + i) * NC + lrow] = acc[g * 4 + rr];
            if (lrow == 0) pdsum[(size_t)q * NPAD + i] = asum[g * 4 + rr];
        }
}

__global__ void cls_merge(const float* __restrict__ pacc, const float* __restrict__ pdsum,
                          float* __restrict__ outp) {
    int i = blockIdx.x * 8 + (threadIdx.x >> 5);
    int c = threadIdx.x & 31;
    if (i >= NN) return;
    float num = 0.f, den = 0.f;
#pragma unroll
    for (int q = 0; q < 8; ++q) {
        num += pacc[((size_t)q * NPAD + i) * NC + c];
        den += pdsum[(size_t)q * NPAD + i];
    }
    outp[(size_t)i * NC + c] = (den > 0.f) ? num / den : 0.f;
}

// ---------------- launcher ----------------
extern "C" void kernel_launch(void* const* d_in, const int* in_sizes, int n_in,
                              void* d_out, int out_size, void* d_ws, size_t ws_size,
                              hipStream_t stream) {
    const float* features = (const float*)d_in[0];
    const int*   adj      = (const int*)d_in[1];
    const float* W0       = (const float*)d_in[2];
    const float* a10      = (const float*)d_in[3];
    const float* a20      = (const float*)d_in[4];
    const float* Wc       = (const float*)d_in[5];
    const float* a1c      = (const float*)d_in[6];
    const float* a2c      = (const float*)d_in[7];
    float* out = (float*)d_out;

    char* p = (char*)d_ws;
    auto alloc = [&](size_t bytes) { char* r = p; p += (bytes + 255) & ~(size_t)255; return r; };
    unsigned long long* mask = (unsigned long long*)alloc((size_t)NN * MSTR * 8);
    unsigned short* Xbf = (unsigned short*)alloc((size_t)NN * DF * 2);
    unsigned short* Wt  = (unsigned short*)alloc((size_t)FTOT * DF * 2);
    unsigned short* Ht  = (unsigned short*)alloc((size_t)FTOT * NPAD * 2);
    unsigned short* Wct = (unsigned short*)alloc((size_t)NC * FTOT * 2);
    unsigned short* hct = (unsigned short*)alloc((size_t)NC * NPAD * 2);
    float* f1p = (float*)alloc((size_t)4 * NH * NPAD * 4);
    float* f2p = (float*)alloc((size_t)4 * NH * NPAD * 4);
    float* RA  = (float*)alloc((size_t)NH * NPAD * 4);
    float* RB  = (float*)alloc((size_t)NH * NPAD * 4);
    float* E2F  = (float*)alloc((size_t)NH * NPAD * 4);
    float* E2Fb = (float*)alloc((size_t)NH * NPAD * 4);
    float* f1cp = (float*)alloc((size_t)NPAD * 4);
    float* f2cp = (float*)alloc((size_t)NPAD * 4);
    float* RAc  = (float*)alloc((size_t)NPAD * 4);
    float* RBc  = (float*)alloc((size_t)NPAD * 4);
    float* E2Fc  = (float*)alloc((size_t)NPAD * 4);
    float* E2Fcb = (float*)alloc((size_t)NPAD * 4);
    // overlays on dead Xbf+Wt (8.26 MB):
    //   hcp [8][NPAD][32] f32 = 6.16 MB (attn writes, merge_hcp reads)
    //   then pacc 6.16 MB + pdsum 192 KB (cls_part, after hcp is dead)
    float* hcp   = (float*)Xbf;
    float* pacc  = (float*)Xbf;
    float* pdsum = pacc + (size_t)8 * NPAD * NC;

    prep_all<<<NB_PACK + NB_CAST + NB_WT + NB_WCT, 256, 0, stream>>>(
        adj, (unsigned char*)mask, features, Xbf, W0, Wt, Wc, Wct);

    gemm_h<<<dim3(NPAD / 128, FTOT / 128), 256, 0, stream>>>(Xbf, Wt, Ht);
    f12s_kern<<<dim3((NPAD + 255) / 256, NH, 4), 256, 0, stream>>>(Ht, a10, a20, f1p, f2p, HID, 4);
    rarb_kern<<<NH, 256, 0, stream>>>(f1p, f2p, RA, RB, E2F, E2Fb, 4);

    attn_main<<<dim3(94 * NH), 256, 0, stream>>>(Ht, mask, RA, RB, E2F, E2Fb, Wct, hcp);

    merge_hcp<<<(NPAD * NC + 255) / 256, 256, 0, stream>>>(hcp, hct);
    f12s_kern<<<dim3((NPAD + 255) / 256, 1, 1), 256, 0, stream>>>(hct, a1c, a2c, f1cp, f2cp, NC, 1);
    rarb_kern<<<1, 256, 0, stream>>>(f1cp, f2cp, RAc, RBc, E2Fc, E2Fcb, 1);

    cls_part<<<dim3(47, 8), 256, 0, stream>>>(hct, mask, RAc, RBc, E2Fc, E2Fcb, pacc, pdsum);
    cls_merge<<<750, 256, 0, stream>>>(pacc, pdsum, out);
}